// Round 8
// baseline (65.485 us; speedup 1.0000x reference)
//
#include <hip/hip_runtime.h>

#define MAX_FTS 30
#define HALF 256
#define ROWLEN 257

typedef __attribute__((ext_vector_type(8))) _Float16 f16x8;
typedef __attribute__((ext_vector_type(4))) float    f32x4;

// ---------------------------------------------------------------------------
// Prep: per-row int8 quantization (biased uint8 + per-row f32 scale) + psqt
// column; blocks < 69 additionally build MFMA weight fragments + zero row.
// ---------------------------------------------------------------------------
__global__ __launch_bounds__(256) void prep(
    const float* __restrict__ ft_w, const float* __restrict__ fc1_w,
    const float* __restrict__ fc2_w,
    unsigned char* __restrict__ tbl8, float* __restrict__ scl,
    float* __restrict__ psq, _Float16* __restrict__ w1f,
    _Float16* __restrict__ w2f, int n_fts)
{
    const int wv = threadIdx.x >> 6, l = threadIdx.x & 63;
    const int r = blockIdx.x * 4 + wv;
    if (r < n_fts) {
        const float* row = ft_w + (size_t)r * ROWLEN;
        float v[4];
#pragma unroll
        for (int k = 0; k < 4; ++k) v[k] = row[(l << 2) + k];
        float m = fmaxf(fmaxf(fabsf(v[0]), fabsf(v[1])), fmaxf(fabsf(v[2]), fabsf(v[3])));
#pragma unroll
        for (int d = 1; d < 64; d <<= 1) m = fmaxf(m, __shfl_xor(m, d, 64));
        const float s   = m * (1.0f / 127.0f);
        const float inv = (m > 0.0f) ? (127.0f / m) : 0.0f;
        unsigned int u = 0;
#pragma unroll
        for (int k = 0; k < 4; ++k) {
            int q = (int)rintf(v[k] * inv) + 128;
            u |= ((unsigned int)q & 0xffu) << (8 * k);
        }
        *(unsigned int*)(tbl8 + (size_t)r * 256 + (l << 2)) = u;
        if (l == 0) { scl[r] = s; psq[r] = row[HALF]; }
    }

    const int idx = blockIdx.x * 256 + threadIdx.x;
    if (idx < 16384) {
        const int nt = idx >> 13, ks = (idx >> 9) & 15, ln = (idx >> 3) & 63, e = idx & 7;
        w1f[idx] = (_Float16)fc1_w[(nt * 16 + (ln & 15)) * 512 + ks * 32 + (ln >> 4) * 8 + e];
    } else if (idx < 16384 + 1024) {
        const int k = idx - 16384;
        const int n2 = k >> 9, ln = (k >> 3) & 63, e = k & 7;
        w2f[k] = (_Float16)fc2_w[(n2 * 16 + (ln & 15)) * 32 + (ln >> 4) * 8 + e];
    } else if (idx < 16384 + 1024 + 64) {
        ((unsigned int*)(tbl8 + (size_t)n_fts * 256))[idx - 17408] = 0x80808080u;
    } else if (idx == 16384 + 1024 + 64) {
        scl[n_fts] = 0.0f; psq[n_fts] = 0.0f;
    }
}

// ---------------------------------------------------------------------------
// K1: gather/FT, FOUR samples per wave. 16-lane group g owns one sample;
// a row-fetch is 16 lanes x 16B (dwordx4) so one wave instruction carries
// 4 independent rows (16 cache lines). (idx,scale) pairs staged to LDS with
// zero-row clamp applied up front -> branch-free inner loop. Lane holds
// 16 elements of BOTH perspectives -> lerp needs no shuffles.
// ---------------------------------------------------------------------------
__global__ __launch_bounds__(256, 4) void k1_gather4(
    const int* __restrict__ wft, const int* __restrict__ bft,
    const float* __restrict__ stm,
    const unsigned char* __restrict__ tbl8, const float* __restrict__ scl,
    const float* __restrict__ psq, const float* __restrict__ ft_b,
    _Float16* __restrict__ X, float* __restrict__ psterm, int B, int zr)
{
    const int t   = threadIdx.x;
    const int wv  = t >> 6;
    const int l   = t & 63;
    const int sub = l >> 4;        // sample within wave
    const int q   = l & 15;        // lane within 16-group
    const int s   = blockIdx.x * 16 + wv * 4 + sub;
    if (s >= B) return;

    __shared__ int2 s_pair[4][4][2][33];   // [wave][sub][persp][slot] (idx, scl bits)

    // ---- staging: indices, scales, psqt; zero-row clamp applied here ----
    const int base = s * MAX_FTS;
    const int iw0 = wft[base + q];
    const int ib0 = bft[base + q];
    const int iw1 = (q + 16 < MAX_FTS) ? wft[base + q + 16] : -1;
    const int ib1 = (q + 16 < MAX_FTS) ? bft[base + q + 16] : -1;
    const int cw0 = (iw0 < 0) ? zr : iw0;
    const int cw1 = (iw1 < 0) ? zr : iw1;
    const int cb0 = (ib0 < 0) ? zr : ib0;
    const int cb1 = (ib1 < 0) ? zr : ib1;

    const float sw0 = scl[cw0], sw1 = scl[cw1];
    const float sb0 = scl[cb0], sb1 = scl[cb1];
    float pv  = (psq[cw0] + psq[cw1]) - (psq[cb0] + psq[cb1]);
    float ssw = sw0 + sw1;
    float ssb = sb0 + sb1;
#pragma unroll
    for (int d = 1; d < 16; d <<= 1) {
        ssw += __shfl_xor(ssw, d, 64);
        ssb += __shfl_xor(ssb, d, 64);
        pv  += __shfl_xor(pv,  d, 64);
    }

    s_pair[wv][sub][0][q]      = make_int2(cw0, __builtin_bit_cast(int, sw0));
    s_pair[wv][sub][0][q + 16] = make_int2(cw1, __builtin_bit_cast(int, sw1));
    s_pair[wv][sub][1][q]      = make_int2(cb0, __builtin_bit_cast(int, sb0));
    s_pair[wv][sub][1][q + 16] = make_int2(cb1, __builtin_bit_cast(int, sb1));
    __builtin_amdgcn_wave_barrier();
    asm volatile("" ::: "memory");

    const float st = stm[s];
    if (q == 0) psterm[s] = pv * (0.5f - st);

    // ---- branch-free gather: 60 x (ds_read_b64 + global dwordx4 + unpack) ----
    float accw[16], accb[16];
#pragma unroll
    for (int k = 0; k < 16; ++k) { accw[k] = 0.0f; accb[k] = 0.0f; }

    const unsigned char* gb = tbl8 + (q << 4);

#define ACC8(A, off, u, sc)                                      \
    A[(off) + 0] = fmaf(sc, (float)((u)        & 0xffu), A[(off) + 0]); \
    A[(off) + 1] = fmaf(sc, (float)(((u) >> 8) & 0xffu), A[(off) + 1]); \
    A[(off) + 2] = fmaf(sc, (float)(((u) >>16) & 0xffu), A[(off) + 2]); \
    A[(off) + 3] = fmaf(sc, (float)( (u) >>24        ), A[(off) + 3]);

#pragma unroll
    for (int slot = 0; slot < MAX_FTS; ++slot) {
        const int2 pw_ = s_pair[wv][sub][0][slot];
        const uint4 dw = *(const uint4*)(gb + ((size_t)pw_.x << 8));
        const float sw = __builtin_bit_cast(float, pw_.y);
        ACC8(accw, 0,  dw.x, sw)
        ACC8(accw, 4,  dw.y, sw)
        ACC8(accw, 8,  dw.z, sw)
        ACC8(accw, 12, dw.w, sw)

        const int2 pb_ = s_pair[wv][sub][1][slot];
        const uint4 db = *(const uint4*)(gb + ((size_t)pb_.x << 8));
        const float sb = __builtin_bit_cast(float, pb_.y);
        ACC8(accb, 0,  db.x, sb)
        ACC8(accb, 4,  db.y, sb)
        ACC8(accb, 8,  db.z, sb)
        ACC8(accb, 12, db.w, sb)
    }
#undef ACC8

    // ---- epilogue: bias removal, +ft_b, stm lerp, clip, fp16 store ----
    const float os = 1.0f - st;
    const float bw = 128.0f * ssw;
    const float bb = 128.0f * ssb;
    const float* fbp = ft_b + (q << 4);

    f16x8 xl0, xl1, xh0, xh1;
#pragma unroll
    for (int k = 0; k < 16; ++k) {
        const float aw = (accw[k] - bw) + fbp[k];
        const float ab = (accb[k] - bb) + fbp[k];
        const float xl = fminf(fmaxf(os * aw + st * ab, 0.0f), 1.0f);
        const float xh = fminf(fmaxf(os * ab + st * aw, 0.0f), 1.0f);
        if (k < 8) { xl0[k] = (_Float16)xl; xh0[k] = (_Float16)xh; }
        else       { xl1[k - 8] = (_Float16)xl; xh1[k - 8] = (_Float16)xh; }
    }
    _Float16* xp = X + (size_t)s * 512 + (q << 4);
    *(f16x8*)(xp)             = xl0;
    *(f16x8*)(xp + 8)         = xl1;
    *(f16x8*)(xp + HALF)      = xh0;
    *(f16x8*)(xp + HALF + 8)  = xh1;
}

// ---------------------------------------------------------------------------
// K2: batched MLP via MFMA. One wave = 16 samples. FC1: 32 mfma; FC2: 2 mfma;
// FCO: shuffle-reduced dot. D layout: col=lane&15, row=(lane>>4)*4+reg.
// ---------------------------------------------------------------------------
__global__ __launch_bounds__(256) void k2_mlp(
    const _Float16* __restrict__ X,
    const _Float16* __restrict__ w1f, const _Float16* __restrict__ w2f,
    const float* __restrict__ fc1_b, const float* __restrict__ fc2_b,
    const float* __restrict__ fco_w, const float* __restrict__ fco_b,
    const float* __restrict__ psterm, float* __restrict__ out, int B)
{
    const int t   = threadIdx.x;
    const int wv  = t >> 6;
    const int l   = t & 63;
    const int col = l & 15;
    const int qk  = l >> 4;
    const int s0  = blockIdx.x * 64 + wv * 16;
    if (s0 >= B) return;

    __shared__ __attribute__((aligned(16))) _Float16 h1l[4][16][40];

    f32x4 acc0 = {0.0f, 0.0f, 0.0f, 0.0f};
    f32x4 acc1 = {0.0f, 0.0f, 0.0f, 0.0f};
    const _Float16* xp = X + (size_t)(s0 + col) * 512 + qk * 8;
#pragma unroll
    for (int ks = 0; ks < 16; ++ks) {
        const f16x8 a  = *(const f16x8*)(xp + ks * 32);
        const f16x8 b0 = *(const f16x8*)(w1f + ((size_t)(ks)      * 64 + l) * 8);
        const f16x8 b1 = *(const f16x8*)(w1f + ((size_t)(16 + ks) * 64 + l) * 8);
        acc0 = __builtin_amdgcn_mfma_f32_16x16x32_f16(a, b0, acc0, 0, 0, 0);
        acc1 = __builtin_amdgcn_mfma_f32_16x16x32_f16(a, b1, acc1, 0, 0, 0);
    }

    const float b1a = fc1_b[col], b1b = fc1_b[16 + col];
#pragma unroll
    for (int r = 0; r < 4; ++r) {
        h1l[wv][qk * 4 + r][col]      = (_Float16)fminf(fmaxf(acc0[r] + b1a, 0.0f), 1.0f);
        h1l[wv][qk * 4 + r][16 + col] = (_Float16)fminf(fmaxf(acc1[r] + b1b, 0.0f), 1.0f);
    }
    __builtin_amdgcn_wave_barrier();
    asm volatile("" ::: "memory");

    const f16x8 a2  = *(const f16x8*)(&h1l[wv][col][qk * 8]);
    const f16x8 b20 = *(const f16x8*)(w2f + (size_t)l * 8);
    const f16x8 b21 = *(const f16x8*)(w2f + 512 + (size_t)l * 8);
    f32x4 d0 = {0.0f, 0.0f, 0.0f, 0.0f};
    f32x4 d1 = {0.0f, 0.0f, 0.0f, 0.0f};
    d0 = __builtin_amdgcn_mfma_f32_16x16x32_f16(a2, b20, d0, 0, 0, 0);
    d1 = __builtin_amdgcn_mfma_f32_16x16x32_f16(a2, b21, d1, 0, 0, 0);

    const float b2a = fc2_b[col],  b2b = fc2_b[16 + col];
    const float fwa = fco_w[col],  fwb = fco_w[16 + col];
    float p[4];
#pragma unroll
    for (int r = 0; r < 4; ++r) {
        const float h2a = fminf(fmaxf(d0[r] + b2a, 0.0f), 1.0f);
        const float h2b = fminf(fmaxf(d1[r] + b2b, 0.0f), 1.0f);
        p[r] = h2a * fwa + h2b * fwb;
    }
#pragma unroll
    for (int r = 0; r < 4; ++r) {
        p[r] += __shfl_xor(p[r], 1, 64);
        p[r] += __shfl_xor(p[r], 2, 64);
        p[r] += __shfl_xor(p[r], 4, 64);
        p[r] += __shfl_xor(p[r], 8, 64);
    }
    if (col == 0) {
        const float ob = fco_b[0];
#pragma unroll
        for (int r = 0; r < 4; ++r) {
            const int s = s0 + qk * 4 + r;
            out[s] = p[r] + ob + psterm[s];
        }
    }
}

// ---------------------------------------------------------------------------
// Fallback (verified R1 f32 kernel) — used only if ws is too small.
// ---------------------------------------------------------------------------
__global__ __launch_bounds__(256) void nnue_fwd(
    const int* __restrict__ wft, const int* __restrict__ bft,
    const float* __restrict__ stm, const float* __restrict__ ft_w,
    const float* __restrict__ ft_b, const float* __restrict__ fc1_w,
    const float* __restrict__ fc1_b, const float* __restrict__ fc2_w,
    const float* __restrict__ fc2_b, const float* __restrict__ fco_w,
    const float* __restrict__ fco_b, float* __restrict__ out)
{
    const int s = blockIdx.x;
    const int t = threadIdx.x;
    __shared__ int   s_iw[MAX_FTS];
    __shared__ int   s_ib[MAX_FTS];
    __shared__ float s_xx[2 * HALF];
    __shared__ float s_a[32];
    __shared__ float s_b[32];
    __shared__ float s_ps[2];

    if (t < MAX_FTS)                      s_iw[t]      = wft[s * MAX_FTS + t];
    else if (t >= 64 && t < 64 + MAX_FTS) s_ib[t - 64] = bft[s * MAX_FTS + (t - 64)];
    __syncthreads();

    float accw = ft_b[t];
    float accb = ft_b[t];
#pragma unroll
    for (int i = 0; i < MAX_FTS; ++i) {
        int icw = __builtin_amdgcn_readfirstlane(s_iw[i]);
        int icb = __builtin_amdgcn_readfirstlane(s_ib[i]);
        float mw = icw >= 0 ? 1.0f : 0.0f;
        float mb = icb >= 0 ? 1.0f : 0.0f;
        int ow = (icw >= 0 ? icw : 0) * ROWLEN;
        int ob = (icb >= 0 ? icb : 0) * ROWLEN;
        accw = fmaf(ft_w[ow + t], mw, accw);
        accb = fmaf(ft_w[ob + t], mb, accb);
    }
    if (t == 0 || t == 64) {
        const int* idx = (t == 0) ? s_iw : s_ib;
        float ps = 0.0f;
#pragma unroll
        for (int i = 0; i < MAX_FTS; ++i) {
            int ic = idx[i];
            float m = ic >= 0 ? 1.0f : 0.0f;
            int o = (ic >= 0 ? ic : 0) * ROWLEN;
            ps = fmaf(ft_w[o + HALF], m, ps);
        }
        s_ps[t == 0 ? 0 : 1] = ps;
    }
    const float st = stm[s];
    float xl = (1.0f - st) * accw + st * accb;
    float xh = (1.0f - st) * accb + st * accw;
    s_xx[t]        = fminf(fmaxf(xl, 0.0f), 1.0f);
    s_xx[t + HALF] = fminf(fmaxf(xh, 0.0f), 1.0f);
    __syncthreads();

    const int j = t >> 3, p = t & 7;
    const float* w1 = fc1_w + j * (2 * HALF);
    float part = 0.0f;
#pragma unroll
    for (int i = 0; i < 64; ++i) {
        int k = (i << 3) | p;
        part = fmaf(s_xx[k], w1[k], part);
    }
    part += __shfl_xor(part, 1, 64);
    part += __shfl_xor(part, 2, 64);
    part += __shfl_xor(part, 4, 64);
    if (p == 0) s_a[j] = fminf(fmaxf(part + fc1_b[j], 0.0f), 1.0f);
    __syncthreads();

    if (t < 32) {
        float a = fc2_b[t];
        const float* w2 = fc2_w + t * 32;
#pragma unroll
        for (int k = 0; k < 32; ++k) a = fmaf(s_a[k], w2[k], a);
        s_b[t] = fminf(fmaxf(a, 0.0f), 1.0f);
    }
    __syncthreads();

    if (t == 0) {
        float o = fco_b[0];
#pragma unroll
        for (int k = 0; k < 32; ++k) o = fmaf(s_b[k], fco_w[k], o);
        o += (s_ps[0] - s_ps[1]) * (0.5f - st);
        out[s] = o;
    }
}

extern "C" void kernel_launch(void* const* d_in, const int* in_sizes, int n_in,
                              void* d_out, int out_size, void* d_ws, size_t ws_size,
                              hipStream_t stream) {
    const int*   wft   = (const int*)  d_in[0];
    const int*   bft   = (const int*)  d_in[1];
    const float* stm   = (const float*)d_in[2];
    const float* ft_w  = (const float*)d_in[3];
    const float* ft_b  = (const float*)d_in[4];
    const float* fc1_w = (const float*)d_in[5];
    const float* fc1_b = (const float*)d_in[6];
    const float* fc2_w = (const float*)d_in[7];
    const float* fc2_b = (const float*)d_in[8];
    const float* fco_w = (const float*)d_in[9];
    const float* fco_b = (const float*)d_in[10];
    float* out = (float*)d_out;

    const int B     = in_sizes[0] / MAX_FTS;
    const int n_fts = in_sizes[3] / ROWLEN;

    const size_t colpad = (((size_t)(n_fts + 1) * sizeof(float)) + 15) & ~(size_t)15;
    const size_t w1f_b  = 16384 * sizeof(_Float16);           // 32 KB
    const size_t w2f_b  = 1024 * sizeof(_Float16);            // 2 KB
    const size_t pst_b  = ((size_t)B * sizeof(float) + 15) & ~(size_t)15;
    const size_t x_b    = (size_t)B * 512 * sizeof(_Float16); // 16 MB
    const size_t tbl_b  = (size_t)(n_fts + 1) * 256;
    const size_t need   = 2 * colpad + w1f_b + w2f_b + pst_b + x_b + tbl_b;

    const int nbq = (n_fts + 3) / 4;   // >= 69 for this problem size

    if (ws_size >= need && (B & 63) == 0 && nbq >= 69) {
        char* p = (char*)d_ws;
        float*         scl  = (float*)p;                 p += colpad;
        float*         psq  = (float*)p;                 p += colpad;
        _Float16*      w1f  = (_Float16*)p;              p += w1f_b;
        _Float16*      w2f  = (_Float16*)p;              p += w2f_b;
        float*         pst  = (float*)p;                 p += pst_b;
        _Float16*      X    = (_Float16*)p;              p += x_b;
        unsigned char* tbl8 = (unsigned char*)p;

        prep<<<nbq, 256, 0, stream>>>(ft_w, fc1_w, fc2_w, tbl8, scl, psq, w1f, w2f, n_fts);
        k1_gather4<<<B / 16, 256, 0, stream>>>(wft, bft, stm, tbl8, scl, psq,
                                               ft_b, X, pst, B, n_fts);
        k2_mlp<<<B / 64, 256, 0, stream>>>(X, w1f, w2f, fc1_b, fc2_b,
                                           fco_w, fco_b, pst, out, B);
    } else {
        nnue_fwd<<<B, 256, 0, stream>>>(wft, bft, stm, ft_w, ft_b,
                                        fc1_w, fc1_b, fc2_w, fc2_b,
                                        fco_w, fco_b, out);
    }
}

// Round 9
// 56.447 us; speedup vs baseline: 1.1601x; 1.1601x over previous
//
#include <hip/hip_runtime.h>

#define MAX_FTS 30
#define HALF 256
#define ROWLEN 257

typedef __attribute__((ext_vector_type(4))) _Float16 f16x4;
typedef __attribute__((ext_vector_type(8))) _Float16 f16x8;
typedef __attribute__((ext_vector_type(4))) float    f32x4;

// ---------------------------------------------------------------------------
// Prep: per-row int8 quantization (biased uint8 + per-row f32 scale) + psqt
// column; low blocks additionally build MFMA weight fragments + zero row.
// ---------------------------------------------------------------------------
__global__ __launch_bounds__(256) void prep(
    const float* __restrict__ ft_w, const float* __restrict__ fc1_w,
    const float* __restrict__ fc2_w,
    unsigned char* __restrict__ tbl8, float* __restrict__ scl,
    float* __restrict__ psq, _Float16* __restrict__ w1f,
    _Float16* __restrict__ w2f, int n_fts)
{
    const int wv = threadIdx.x >> 6, l = threadIdx.x & 63;
    const int r = blockIdx.x * 4 + wv;
    if (r < n_fts) {
        const float* row = ft_w + (size_t)r * ROWLEN;
        float v[4];
#pragma unroll
        for (int k = 0; k < 4; ++k) v[k] = row[(l << 2) + k];
        float m = fmaxf(fmaxf(fabsf(v[0]), fabsf(v[1])), fmaxf(fabsf(v[2]), fabsf(v[3])));
#pragma unroll
        for (int d = 1; d < 64; d <<= 1) m = fmaxf(m, __shfl_xor(m, d, 64));
        const float s   = m * (1.0f / 127.0f);
        const float inv = (m > 0.0f) ? (127.0f / m) : 0.0f;
        unsigned int u = 0;
#pragma unroll
        for (int k = 0; k < 4; ++k) {
            int q = (int)rintf(v[k] * inv) + 128;
            u |= ((unsigned int)q & 0xffu) << (8 * k);
        }
        *(unsigned int*)(tbl8 + (size_t)r * 256 + (l << 2)) = u;
        if (l == 0) { scl[r] = s; psq[r] = row[HALF]; }
    }

    const int idx = blockIdx.x * 256 + threadIdx.x;
    if (idx < 16384) {
        const int nt = idx >> 13, ks = (idx >> 9) & 15, ln = (idx >> 3) & 63, e = idx & 7;
        w1f[idx] = (_Float16)fc1_w[(nt * 16 + (ln & 15)) * 512 + ks * 32 + (ln >> 4) * 8 + e];
    } else if (idx < 16384 + 1024) {
        const int k = idx - 16384;
        const int n2 = k >> 9, ln = (k >> 3) & 63, e = k & 7;
        w2f[k] = (_Float16)fc2_w[(n2 * 16 + (ln & 15)) * 32 + (ln >> 4) * 8 + e];
    } else if (idx < 16384 + 1024 + 64) {
        ((unsigned int*)(tbl8 + (size_t)n_fts * 256))[idx - 17408] = 0x80808080u;
    } else if (idx == 16384 + 1024 + 64) {
        scl[n_fts] = 0.0f; psq[n_fts] = 0.0f;
    }
}

// ---------------------------------------------------------------------------
// Fused kernel: 512 threads = 8 waves; each wave gathers TWO samples with
// R7's proven per-sample structure (two independent scalar acc chains ->
// 2x loads in flight). x staged to LDS; after one barrier, wave 0 runs the
// verified MFMA MLP for the block's 16 samples and writes out directly.
// ---------------------------------------------------------------------------
__global__ __launch_bounds__(512) void k_fused(
    const int* __restrict__ wft, const int* __restrict__ bft,
    const float* __restrict__ stm,
    const unsigned char* __restrict__ tbl8, const float* __restrict__ scl,
    const float* __restrict__ psq, const float* __restrict__ ft_b,
    const _Float16* __restrict__ w1f, const _Float16* __restrict__ w2f,
    const float* __restrict__ fc1_b, const float* __restrict__ fc2_b,
    const float* __restrict__ fco_w, const float* __restrict__ fco_b,
    float* __restrict__ out, int zr)
{
    const int t  = threadIdx.x;
    const int wv = t >> 6;             // 0..7
    const int l  = t & 63;
    const int s0 = blockIdx.x * 16 + wv * 2;
    const int s1 = s0 + 1;

    __shared__ __attribute__((aligned(16))) _Float16 Xl[16][520]; // padded rows
    __shared__ __attribute__((aligned(16))) _Float16 h1l[16][40];
    __shared__ float ps_l[16];

    // ---- index prefetch for both samples ----
    const int lc  = (l < MAX_FTS) ? l : (MAX_FTS - 1);
    const int iw0 = wft[s0 * MAX_FTS + lc];
    const int ib0 = bft[s0 * MAX_FTS + lc];
    const int iw1 = wft[s1 * MAX_FTS + lc];
    const int ib1 = bft[s1 * MAX_FTS + lc];
    const int cw0 = (iw0 < 0) ? zr : iw0;
    const int cb0 = (ib0 < 0) ? zr : ib0;
    const int cw1 = (iw1 < 0) ? zr : iw1;
    const int cb1 = (ib1 < 0) ? zr : ib1;

    float sw0_ = 0.0f, sb0_ = 0.0f, pv0 = 0.0f;
    float sw1_ = 0.0f, sb1_ = 0.0f, pv1 = 0.0f;
    if (l < MAX_FTS) {
        sw0_ = scl[cw0]; sb0_ = scl[cb0]; pv0 = psq[cw0] - psq[cb0];
        sw1_ = scl[cw1]; sb1_ = scl[cb1]; pv1 = psq[cw1] - psq[cb1];
    }
    const int sw0i = __builtin_bit_cast(int, sw0_);
    const int sb0i = __builtin_bit_cast(int, sb0_);
    const int sw1i = __builtin_bit_cast(int, sw1_);
    const int sb1i = __builtin_bit_cast(int, sb1_);

    // ---- 120 unconditional int8 row gathers, two independent chains ----
    f32x4 aw0 = {0,0,0,0}, ab0 = {0,0,0,0}, aw1 = {0,0,0,0}, ab1 = {0,0,0,0};
    const unsigned char* gb = tbl8 + (l << 2);

#define ACC4(A, u, sc)                                   \
    A[0] = fmaf(sc, (float)( (u)        & 0xffu), A[0]); \
    A[1] = fmaf(sc, (float)(((u) >>  8) & 0xffu), A[1]); \
    A[2] = fmaf(sc, (float)(((u) >> 16) & 0xffu), A[2]); \
    A[3] = fmaf(sc, (float)( (u) >> 24        ),  A[3]);

#pragma unroll
    for (int i = 0; i < MAX_FTS; ++i) {
        int a = __builtin_amdgcn_readlane(iw0, i); a = (a < 0) ? zr : a;
        const unsigned int qa = *(const unsigned int*)(gb + ((size_t)a << 8));
        const float fa = __builtin_bit_cast(float, __builtin_amdgcn_readlane(sw0i, i));
        ACC4(aw0, qa, fa)

        int b = __builtin_amdgcn_readlane(ib0, i); b = (b < 0) ? zr : b;
        const unsigned int qb = *(const unsigned int*)(gb + ((size_t)b << 8));
        const float fb_ = __builtin_bit_cast(float, __builtin_amdgcn_readlane(sb0i, i));
        ACC4(ab0, qb, fb_)

        int c = __builtin_amdgcn_readlane(iw1, i); c = (c < 0) ? zr : c;
        const unsigned int qc = *(const unsigned int*)(gb + ((size_t)c << 8));
        const float fc_ = __builtin_bit_cast(float, __builtin_amdgcn_readlane(sw1i, i));
        ACC4(aw1, qc, fc_)

        int d = __builtin_amdgcn_readlane(ib1, i); d = (d < 0) ? zr : d;
        const unsigned int qd = *(const unsigned int*)(gb + ((size_t)d << 8));
        const float fd = __builtin_bit_cast(float, __builtin_amdgcn_readlane(sb1i, i));
        ACC4(ab1, qd, fd)
    }
#undef ACC4

    // ---- butterflies: scale sums + psqt diffs ----
    float ssw0 = sw0_, ssb0 = sb0_, ssw1 = sw1_, ssb1 = sb1_;
#pragma unroll
    for (int d = 1; d < 64; d <<= 1) {
        ssw0 += __shfl_xor(ssw0, d, 64);
        ssb0 += __shfl_xor(ssb0, d, 64);
        ssw1 += __shfl_xor(ssw1, d, 64);
        ssb1 += __shfl_xor(ssb1, d, 64);
        pv0  += __shfl_xor(pv0,  d, 64);
        pv1  += __shfl_xor(pv1,  d, 64);
    }

    // ---- epilogue both samples: bias removal, +ft_b, lerp, clip, LDS ----
    const f32x4 fb = *(const f32x4*)(ft_b + (l << 2));
    const float st0 = stm[s0], st1 = stm[s1];
    const float os0 = 1.0f - st0, os1 = 1.0f - st1;
    const float bw0 = 128.0f * ssw0, bb0 = 128.0f * ssb0;
    const float bw1 = 128.0f * ssw1, bb1 = 128.0f * ssb1;

    f16x4 xl0, xh0, xl1, xh1;
#pragma unroll
    for (int k = 0; k < 4; ++k) {
        const float a0 = (aw0[k] - bw0) + fb[k];
        const float b0 = (ab0[k] - bb0) + fb[k];
        xl0[k] = (_Float16)fminf(fmaxf(os0 * a0 + st0 * b0, 0.0f), 1.0f);
        xh0[k] = (_Float16)fminf(fmaxf(os0 * b0 + st0 * a0, 0.0f), 1.0f);
        const float a1 = (aw1[k] - bw1) + fb[k];
        const float b1 = (ab1[k] - bb1) + fb[k];
        xl1[k] = (_Float16)fminf(fmaxf(os1 * a1 + st1 * b1, 0.0f), 1.0f);
        xh1[k] = (_Float16)fminf(fmaxf(os1 * b1 + st1 * a1, 0.0f), 1.0f);
    }
    const int sb0_loc = wv * 2, sb1_loc = wv * 2 + 1;
    *(f16x4*)(&Xl[sb0_loc][(l << 2)])        = xl0;
    *(f16x4*)(&Xl[sb0_loc][HALF + (l << 2)]) = xh0;
    *(f16x4*)(&Xl[sb1_loc][(l << 2)])        = xl1;
    *(f16x4*)(&Xl[sb1_loc][HALF + (l << 2)]) = xh1;
    if (l == 0) {
        ps_l[sb0_loc] = pv0 * (0.5f - st0);
        ps_l[sb1_loc] = pv1 * (0.5f - st1);
    }
    __syncthreads();
    if (wv != 0) return;

    // ---- MLP for the block's 16 samples (wave 0 only), verified K2 logic ----
    const int col = l & 15;
    const int qk  = l >> 4;

    f32x4 acc0 = {0,0,0,0}, acc1 = {0,0,0,0};
#pragma unroll
    for (int ks = 0; ks < 16; ++ks) {
        const f16x8 a  = *(const f16x8*)(&Xl[col][ks * 32 + qk * 8]);
        const f16x8 b0 = *(const f16x8*)(w1f + ((size_t)(ks)      * 64 + l) * 8);
        const f16x8 b1 = *(const f16x8*)(w1f + ((size_t)(16 + ks) * 64 + l) * 8);
        acc0 = __builtin_amdgcn_mfma_f32_16x16x32_f16(a, b0, acc0, 0, 0, 0);
        acc1 = __builtin_amdgcn_mfma_f32_16x16x32_f16(a, b1, acc1, 0, 0, 0);
    }

    const float b1a = fc1_b[col], b1b = fc1_b[16 + col];
#pragma unroll
    for (int r = 0; r < 4; ++r) {
        h1l[qk * 4 + r][col]      = (_Float16)fminf(fmaxf(acc0[r] + b1a, 0.0f), 1.0f);
        h1l[qk * 4 + r][16 + col] = (_Float16)fminf(fmaxf(acc1[r] + b1b, 0.0f), 1.0f);
    }
    __builtin_amdgcn_wave_barrier();
    asm volatile("" ::: "memory");

    const f16x8 a2  = *(const f16x8*)(&h1l[col][qk * 8]);
    const f16x8 b20 = *(const f16x8*)(w2f + (size_t)l * 8);
    const f16x8 b21 = *(const f16x8*)(w2f + 512 + (size_t)l * 8);
    f32x4 d0 = {0,0,0,0}, d1 = {0,0,0,0};
    d0 = __builtin_amdgcn_mfma_f32_16x16x32_f16(a2, b20, d0, 0, 0, 0);
    d1 = __builtin_amdgcn_mfma_f32_16x16x32_f16(a2, b21, d1, 0, 0, 0);

    const float b2a = fc2_b[col],  b2b = fc2_b[16 + col];
    const float fwa = fco_w[col],  fwb = fco_w[16 + col];
    float p[4];
#pragma unroll
    for (int r = 0; r < 4; ++r) {
        const float h2a = fminf(fmaxf(d0[r] + b2a, 0.0f), 1.0f);
        const float h2b = fminf(fmaxf(d1[r] + b2b, 0.0f), 1.0f);
        p[r] = h2a * fwa + h2b * fwb;
    }
#pragma unroll
    for (int r = 0; r < 4; ++r) {
        p[r] += __shfl_xor(p[r], 1, 64);
        p[r] += __shfl_xor(p[r], 2, 64);
        p[r] += __shfl_xor(p[r], 4, 64);
        p[r] += __shfl_xor(p[r], 8, 64);
    }
    if (col == 0) {
        const float ob = fco_b[0];
#pragma unroll
        for (int r = 0; r < 4; ++r) {
            const int sloc = qk * 4 + r;
            out[blockIdx.x * 16 + sloc] = p[r] + ob + ps_l[sloc];
        }
    }
}

// ---------------------------------------------------------------------------
// Fallback (verified R1 f32 kernel) — used only if ws is too small.
// ---------------------------------------------------------------------------
__global__ __launch_bounds__(256) void nnue_fwd(
    const int* __restrict__ wft, const int* __restrict__ bft,
    const float* __restrict__ stm, const float* __restrict__ ft_w,
    const float* __restrict__ ft_b, const float* __restrict__ fc1_w,
    const float* __restrict__ fc1_b, const float* __restrict__ fc2_w,
    const float* __restrict__ fc2_b, const float* __restrict__ fco_w,
    const float* __restrict__ fco_b, float* __restrict__ out)
{
    const int s = blockIdx.x;
    const int t = threadIdx.x;
    __shared__ int   s_iw[MAX_FTS];
    __shared__ int   s_ib[MAX_FTS];
    __shared__ float s_xx[2 * HALF];
    __shared__ float s_a[32];
    __shared__ float s_b[32];
    __shared__ float s_ps[2];

    if (t < MAX_FTS)                      s_iw[t]      = wft[s * MAX_FTS + t];
    else if (t >= 64 && t < 64 + MAX_FTS) s_ib[t - 64] = bft[s * MAX_FTS + (t - 64)];
    __syncthreads();

    float accw = ft_b[t];
    float accb = ft_b[t];
#pragma unroll
    for (int i = 0; i < MAX_FTS; ++i) {
        int icw = __builtin_amdgcn_readfirstlane(s_iw[i]);
        int icb = __builtin_amdgcn_readfirstlane(s_ib[i]);
        float mw = icw >= 0 ? 1.0f : 0.0f;
        float mb = icb >= 0 ? 1.0f : 0.0f;
        int ow = (icw >= 0 ? icw : 0) * ROWLEN;
        int ob = (icb >= 0 ? icb : 0) * ROWLEN;
        accw = fmaf(ft_w[ow + t], mw, accw);
        accb = fmaf(ft_w[ob + t], mb, accb);
    }
    if (t == 0 || t == 64) {
        const int* idx = (t == 0) ? s_iw : s_ib;
        float ps = 0.0f;
#pragma unroll
        for (int i = 0; i < MAX_FTS; ++i) {
            int ic = idx[i];
            float m = ic >= 0 ? 1.0f : 0.0f;
            int o = (ic >= 0 ? ic : 0) * ROWLEN;
            ps = fmaf(ft_w[o + HALF], m, ps);
        }
        s_ps[t == 0 ? 0 : 1] = ps;
    }
    const float st = stm[s];
    float xl = (1.0f - st) * accw + st * accb;
    float xh = (1.0f - st) * accb + st * accw;
    s_xx[t]        = fminf(fmaxf(xl, 0.0f), 1.0f);
    s_xx[t + HALF] = fminf(fmaxf(xh, 0.0f), 1.0f);
    __syncthreads();

    const int j = t >> 3, p = t & 7;
    const float* w1 = fc1_w + j * (2 * HALF);
    float part = 0.0f;
#pragma unroll
    for (int i = 0; i < 64; ++i) {
        int k = (i << 3) | p;
        part = fmaf(s_xx[k], w1[k], part);
    }
    part += __shfl_xor(part, 1, 64);
    part += __shfl_xor(part, 2, 64);
    part += __shfl_xor(part, 4, 64);
    if (p == 0) s_a[j] = fminf(fmaxf(part + fc1_b[j], 0.0f), 1.0f);
    __syncthreads();

    if (t < 32) {
        float a = fc2_b[t];
        const float* w2 = fc2_w + t * 32;
#pragma unroll
        for (int k = 0; k < 32; ++k) a = fmaf(s_a[k], w2[k], a);
        s_b[t] = fminf(fmaxf(a, 0.0f), 1.0f);
    }
    __syncthreads();

    if (t == 0) {
        float o = fco_b[0];
#pragma unroll
        for (int k = 0; k < 32; ++k) o = fmaf(s_b[k], fco_w[k], o);
        o += (s_ps[0] - s_ps[1]) * (0.5f - st);
        out[s] = o;
    }
}

extern "C" void kernel_launch(void* const* d_in, const int* in_sizes, int n_in,
                              void* d_out, int out_size, void* d_ws, size_t ws_size,
                              hipStream_t stream) {
    const int*   wft   = (const int*)  d_in[0];
    const int*   bft   = (const int*)  d_in[1];
    const float* stm   = (const float*)d_in[2];
    const float* ft_w  = (const float*)d_in[3];
    const float* ft_b  = (const float*)d_in[4];
    const float* fc1_w = (const float*)d_in[5];
    const float* fc1_b = (const float*)d_in[6];
    const float* fc2_w = (const float*)d_in[7];
    const float* fc2_b = (const float*)d_in[8];
    const float* fco_w = (const float*)d_in[9];
    const float* fco_b = (const float*)d_in[10];
    float* out = (float*)d_out;

    const int B     = in_sizes[0] / MAX_FTS;
    const int n_fts = in_sizes[3] / ROWLEN;

    const size_t colpad = (((size_t)(n_fts + 1) * sizeof(float)) + 15) & ~(size_t)15;
    const size_t w1f_b  = 16384 * sizeof(_Float16);           // 32 KB
    const size_t w2f_b  = 1024 * sizeof(_Float16);            // 2 KB
    const size_t tbl_b  = (size_t)(n_fts + 1) * 256;
    const size_t need   = 2 * colpad + w1f_b + w2f_b + tbl_b;

    const int nbq = (n_fts + 3) / 4;   // must cover frag-building range too

    if (ws_size >= need && (B & 15) == 0 && nbq >= 69) {
        char* p = (char*)d_ws;
        float*         scl  = (float*)p;                 p += colpad;
        float*         psq  = (float*)p;                 p += colpad;
        _Float16*      w1f  = (_Float16*)p;              p += w1f_b;
        _Float16*      w2f  = (_Float16*)p;              p += w2f_b;
        unsigned char* tbl8 = (unsigned char*)p;

        prep<<<nbq, 256, 0, stream>>>(ft_w, fc1_w, fc2_w, tbl8, scl, psq, w1f, w2f, n_fts);
        k_fused<<<B / 16, 512, 0, stream>>>(wft, bft, stm, tbl8, scl, psq, ft_b,
                                            w1f, w2f, fc1_b, fc2_b, fco_w, fco_b,
                                            out, n_fts);
    } else {
        nnue_fwd<<<B, 256, 0, stream>>>(wft, bft, stm, ft_w, ft_b,
                                        fc1_w, fc1_b, fc2_w, fc2_b,
                                        fco_w, fco_b, out);
    }
}

// Round 10
// 53.292 us; speedup vs baseline: 1.2288x; 1.0592x over previous
//
#include <hip/hip_runtime.h>

#define MAX_FTS 30
#define HALF 256
#define ROWLEN 257

typedef __attribute__((ext_vector_type(4))) _Float16 f16x4;
typedef __attribute__((ext_vector_type(8))) _Float16 f16x8;
typedef __attribute__((ext_vector_type(4))) float    f32x4;

// ---------------------------------------------------------------------------
// Prep: per-row int8 quantization (biased uint8 + per-row f32 scale) + psqt
// column. TWO rows per wave (independent chains). Low blocks also build the
// MFMA weight fragments + zero row sentinel.
// ---------------------------------------------------------------------------
__global__ __launch_bounds__(256) void prep(
    const float* __restrict__ ft_w, const float* __restrict__ fc1_w,
    const float* __restrict__ fc2_w,
    unsigned char* __restrict__ tbl8, float* __restrict__ scl,
    float* __restrict__ psq, _Float16* __restrict__ w1f,
    _Float16* __restrict__ w2f, int n_fts)
{
    const int wv = threadIdx.x >> 6, l = threadIdx.x & 63;
    const int r0 = blockIdx.x * 8 + wv * 2;
    const int r1 = r0 + 1;

    if (r0 < n_fts) {
        const bool has1 = (r1 < n_fts);
        const float* row0 = ft_w + (size_t)r0 * ROWLEN;
        const float* row1 = ft_w + (size_t)(has1 ? r1 : r0) * ROWLEN;
        f32x4 v0 = *(const f32x4*)(row0 + (l << 2));
        f32x4 v1 = *(const f32x4*)(row1 + (l << 2));

        float m0 = fmaxf(fmaxf(fabsf(v0[0]), fabsf(v0[1])), fmaxf(fabsf(v0[2]), fabsf(v0[3])));
        float m1 = fmaxf(fmaxf(fabsf(v1[0]), fabsf(v1[1])), fmaxf(fabsf(v1[2]), fabsf(v1[3])));
#pragma unroll
        for (int d = 1; d < 64; d <<= 1) {
            m0 = fmaxf(m0, __shfl_xor(m0, d, 64));
            m1 = fmaxf(m1, __shfl_xor(m1, d, 64));
        }
        const float s0   = m0 * (1.0f / 127.0f);
        const float inv0 = (m0 > 0.0f) ? (127.0f / m0) : 0.0f;
        const float s1   = m1 * (1.0f / 127.0f);
        const float inv1 = (m1 > 0.0f) ? (127.0f / m1) : 0.0f;

        unsigned int u0 = 0, u1 = 0;
#pragma unroll
        for (int k = 0; k < 4; ++k) {
            int q0 = (int)rintf(v0[k] * inv0) + 128;
            int q1 = (int)rintf(v1[k] * inv1) + 128;
            u0 |= ((unsigned int)q0 & 0xffu) << (8 * k);
            u1 |= ((unsigned int)q1 & 0xffu) << (8 * k);
        }
        *(unsigned int*)(tbl8 + (size_t)r0 * 256 + (l << 2)) = u0;
        if (has1) *(unsigned int*)(tbl8 + (size_t)r1 * 256 + (l << 2)) = u1;
        if (l == 0) {
            scl[r0] = s0; psq[r0] = row0[HALF];
            if (has1) { scl[r1] = s1; psq[r1] = row1[HALF]; }
        }
    }

    const int idx = blockIdx.x * 256 + threadIdx.x;
    if (idx < 16384) {
        const int nt = idx >> 13, ks = (idx >> 9) & 15, ln = (idx >> 3) & 63, e = idx & 7;
        w1f[idx] = (_Float16)fc1_w[(nt * 16 + (ln & 15)) * 512 + ks * 32 + (ln >> 4) * 8 + e];
    } else if (idx < 16384 + 1024) {
        const int k = idx - 16384;
        const int n2 = k >> 9, ln = (k >> 3) & 63, e = k & 7;
        w2f[k] = (_Float16)fc2_w[(n2 * 16 + (ln & 15)) * 32 + (ln >> 4) * 8 + e];
    } else if (idx < 16384 + 1024 + 64) {
        ((unsigned int*)(tbl8 + (size_t)n_fts * 256))[idx - 17408] = 0x80808080u;
    } else if (idx == 16384 + 1024 + 64) {
        scl[n_fts] = 0.0f; psq[n_fts] = 0.0f;
    }
}

// ---------------------------------------------------------------------------
// Fused kernel: 512 threads = 8 waves x 2 samples (R9's proven gather).
// MLP split: wave 0 computes fc1 ntile0, wave 1 ntile1 (16 MFMA each);
// after the second barrier wave 0 finishes fc2/fco. All waves participate
// in both __syncthreads (no exited-wave barriers).
// ---------------------------------------------------------------------------
__global__ __launch_bounds__(512) void k_fused(
    const int* __restrict__ wft, const int* __restrict__ bft,
    const float* __restrict__ stm,
    const unsigned char* __restrict__ tbl8, const float* __restrict__ scl,
    const float* __restrict__ psq, const float* __restrict__ ft_b,
    const _Float16* __restrict__ w1f, const _Float16* __restrict__ w2f,
    const float* __restrict__ fc1_b, const float* __restrict__ fc2_b,
    const float* __restrict__ fco_w, const float* __restrict__ fco_b,
    float* __restrict__ out, int zr)
{
    const int t  = threadIdx.x;
    const int wv = t >> 6;             // 0..7
    const int l  = t & 63;
    const int s0 = blockIdx.x * 16 + wv * 2;
    const int s1 = s0 + 1;

    __shared__ __attribute__((aligned(16))) _Float16 Xl[16][520]; // padded rows
    __shared__ __attribute__((aligned(16))) _Float16 h1l[16][40];
    __shared__ float ps_l[16];

    // ---- index prefetch for both samples ----
    const int lc  = (l < MAX_FTS) ? l : (MAX_FTS - 1);
    const int iw0 = wft[s0 * MAX_FTS + lc];
    const int ib0 = bft[s0 * MAX_FTS + lc];
    const int iw1 = wft[s1 * MAX_FTS + lc];
    const int ib1 = bft[s1 * MAX_FTS + lc];
    const int cw0 = (iw0 < 0) ? zr : iw0;
    const int cb0 = (ib0 < 0) ? zr : ib0;
    const int cw1 = (iw1 < 0) ? zr : iw1;
    const int cb1 = (ib1 < 0) ? zr : ib1;

    float sw0_ = 0.0f, sb0_ = 0.0f, pv0 = 0.0f;
    float sw1_ = 0.0f, sb1_ = 0.0f, pv1 = 0.0f;
    if (l < MAX_FTS) {
        sw0_ = scl[cw0]; sb0_ = scl[cb0]; pv0 = psq[cw0] - psq[cb0];
        sw1_ = scl[cw1]; sb1_ = scl[cb1]; pv1 = psq[cw1] - psq[cb1];
    }
    const int sw0i = __builtin_bit_cast(int, sw0_);
    const int sb0i = __builtin_bit_cast(int, sb0_);
    const int sw1i = __builtin_bit_cast(int, sw1_);
    const int sb1i = __builtin_bit_cast(int, sb1_);

    // ---- 120 unconditional int8 row gathers, four independent chains ----
    f32x4 aw0 = {0,0,0,0}, ab0 = {0,0,0,0}, aw1 = {0,0,0,0}, ab1 = {0,0,0,0};
    const unsigned char* gb = tbl8 + (l << 2);

#define ACC4(A, u, sc)                                   \
    A[0] = fmaf(sc, (float)( (u)        & 0xffu), A[0]); \
    A[1] = fmaf(sc, (float)(((u) >>  8) & 0xffu), A[1]); \
    A[2] = fmaf(sc, (float)(((u) >> 16) & 0xffu), A[2]); \
    A[3] = fmaf(sc, (float)( (u) >> 24        ),  A[3]);

#pragma unroll
    for (int i = 0; i < MAX_FTS; ++i) {
        int a = __builtin_amdgcn_readlane(iw0, i); a = (a < 0) ? zr : a;
        const unsigned int qa = *(const unsigned int*)(gb + ((size_t)a << 8));
        const float fa = __builtin_bit_cast(float, __builtin_amdgcn_readlane(sw0i, i));
        ACC4(aw0, qa, fa)

        int b = __builtin_amdgcn_readlane(ib0, i); b = (b < 0) ? zr : b;
        const unsigned int qb = *(const unsigned int*)(gb + ((size_t)b << 8));
        const float fb_ = __builtin_bit_cast(float, __builtin_amdgcn_readlane(sb0i, i));
        ACC4(ab0, qb, fb_)

        int c = __builtin_amdgcn_readlane(iw1, i); c = (c < 0) ? zr : c;
        const unsigned int qc = *(const unsigned int*)(gb + ((size_t)c << 8));
        const float fc_ = __builtin_bit_cast(float, __builtin_amdgcn_readlane(sw1i, i));
        ACC4(aw1, qc, fc_)

        int d = __builtin_amdgcn_readlane(ib1, i); d = (d < 0) ? zr : d;
        const unsigned int qd = *(const unsigned int*)(gb + ((size_t)d << 8));
        const float fd = __builtin_bit_cast(float, __builtin_amdgcn_readlane(sb1i, i));
        ACC4(ab1, qd, fd)
    }
#undef ACC4

    // ---- butterflies: scale sums + psqt diffs ----
    float ssw0 = sw0_, ssb0 = sb0_, ssw1 = sw1_, ssb1 = sb1_;
#pragma unroll
    for (int d = 1; d < 64; d <<= 1) {
        ssw0 += __shfl_xor(ssw0, d, 64);
        ssb0 += __shfl_xor(ssb0, d, 64);
        ssw1 += __shfl_xor(ssw1, d, 64);
        ssb1 += __shfl_xor(ssb1, d, 64);
        pv0  += __shfl_xor(pv0,  d, 64);
        pv1  += __shfl_xor(pv1,  d, 64);
    }

    // ---- epilogue both samples: bias removal, +ft_b, lerp, clip, LDS ----
    const f32x4 fb = *(const f32x4*)(ft_b + (l << 2));
    const float st0 = stm[s0], st1 = stm[s1];
    const float os0 = 1.0f - st0, os1 = 1.0f - st1;
    const float bw0 = 128.0f * ssw0, bb0 = 128.0f * ssb0;
    const float bw1 = 128.0f * ssw1, bb1 = 128.0f * ssb1;

    f16x4 xl0, xh0, xl1, xh1;
#pragma unroll
    for (int k = 0; k < 4; ++k) {
        const float a0 = (aw0[k] - bw0) + fb[k];
        const float b0 = (ab0[k] - bb0) + fb[k];
        xl0[k] = (_Float16)fminf(fmaxf(os0 * a0 + st0 * b0, 0.0f), 1.0f);
        xh0[k] = (_Float16)fminf(fmaxf(os0 * b0 + st0 * a0, 0.0f), 1.0f);
        const float a1 = (aw1[k] - bw1) + fb[k];
        const float b1 = (ab1[k] - bb1) + fb[k];
        xl1[k] = (_Float16)fminf(fmaxf(os1 * a1 + st1 * b1, 0.0f), 1.0f);
        xh1[k] = (_Float16)fminf(fmaxf(os1 * b1 + st1 * a1, 0.0f), 1.0f);
    }
    const int sb0_loc = wv * 2, sb1_loc = wv * 2 + 1;
    *(f16x4*)(&Xl[sb0_loc][(l << 2)])        = xl0;
    *(f16x4*)(&Xl[sb0_loc][HALF + (l << 2)]) = xh0;
    *(f16x4*)(&Xl[sb1_loc][(l << 2)])        = xl1;
    *(f16x4*)(&Xl[sb1_loc][HALF + (l << 2)]) = xh1;
    if (l == 0) {
        ps_l[sb0_loc] = pv0 * (0.5f - st0);
        ps_l[sb1_loc] = pv1 * (0.5f - st1);
    }
    __syncthreads();

    const int col = l & 15;
    const int qk  = l >> 4;

    // ---- FC1 split: wave 0 -> ntile 0, wave 1 -> ntile 1 (16 MFMA each) ----
    if (wv < 2) {
        f32x4 acc = {0,0,0,0};
#pragma unroll
        for (int ks = 0; ks < 16; ++ks) {
            const f16x8 a = *(const f16x8*)(&Xl[col][ks * 32 + qk * 8]);
            const f16x8 bfr = *(const f16x8*)(w1f + ((size_t)(wv * 16 + ks) * 64 + l) * 8);
            acc = __builtin_amdgcn_mfma_f32_16x16x32_f16(a, bfr, acc, 0, 0, 0);
        }
        const float b1 = fc1_b[wv * 16 + col];
#pragma unroll
        for (int r = 0; r < 4; ++r)
            h1l[qk * 4 + r][wv * 16 + col] = (_Float16)fminf(fmaxf(acc[r] + b1, 0.0f), 1.0f);
    }
    __syncthreads();
    if (wv != 0) return;

    // ---- FC2 + FCO on wave 0 ----
    const f16x8 a2  = *(const f16x8*)(&h1l[col][qk * 8]);
    const f16x8 b20 = *(const f16x8*)(w2f + (size_t)l * 8);
    const f16x8 b21 = *(const f16x8*)(w2f + 512 + (size_t)l * 8);
    f32x4 d0 = {0,0,0,0}, d1 = {0,0,0,0};
    d0 = __builtin_amdgcn_mfma_f32_16x16x32_f16(a2, b20, d0, 0, 0, 0);
    d1 = __builtin_amdgcn_mfma_f32_16x16x32_f16(a2, b21, d1, 0, 0, 0);

    const float b2a = fc2_b[col],  b2b = fc2_b[16 + col];
    const float fwa = fco_w[col],  fwb = fco_w[16 + col];
    float p[4];
#pragma unroll
    for (int r = 0; r < 4; ++r) {
        const float h2a = fminf(fmaxf(d0[r] + b2a, 0.0f), 1.0f);
        const float h2b = fminf(fmaxf(d1[r] + b2b, 0.0f), 1.0f);
        p[r] = h2a * fwa + h2b * fwb;
    }
#pragma unroll
    for (int r = 0; r < 4; ++r) {
        p[r] += __shfl_xor(p[r], 1, 64);
        p[r] += __shfl_xor(p[r], 2, 64);
        p[r] += __shfl_xor(p[r], 4, 64);
        p[r] += __shfl_xor(p[r], 8, 64);
    }
    if (col == 0) {
        const float ob = fco_b[0];
#pragma unroll
        for (int r = 0; r < 4; ++r) {
            const int sloc = qk * 4 + r;
            out[blockIdx.x * 16 + sloc] = p[r] + ob + ps_l[sloc];
        }
    }
}

// ---------------------------------------------------------------------------
// Fallback (verified R1 f32 kernel) — used only if ws is too small.
// ---------------------------------------------------------------------------
__global__ __launch_bounds__(256) void nnue_fwd(
    const int* __restrict__ wft, const int* __restrict__ bft,
    const float* __restrict__ stm, const float* __restrict__ ft_w,
    const float* __restrict__ ft_b, const float* __restrict__ fc1_w,
    const float* __restrict__ fc1_b, const float* __restrict__ fc2_w,
    const float* __restrict__ fc2_b, const float* __restrict__ fco_w,
    const float* __restrict__ fco_b, float* __restrict__ out)
{
    const int s = blockIdx.x;
    const int t = threadIdx.x;
    __shared__ int   s_iw[MAX_FTS];
    __shared__ int   s_ib[MAX_FTS];
    __shared__ float s_xx[2 * HALF];
    __shared__ float s_a[32];
    __shared__ float s_b[32];
    __shared__ float s_ps[2];

    if (t < MAX_FTS)                      s_iw[t]      = wft[s * MAX_FTS + t];
    else if (t >= 64 && t < 64 + MAX_FTS) s_ib[t - 64] = bft[s * MAX_FTS + (t - 64)];
    __syncthreads();

    float accw = ft_b[t];
    float accb = ft_b[t];
#pragma unroll
    for (int i = 0; i < MAX_FTS; ++i) {
        int icw = __builtin_amdgcn_readfirstlane(s_iw[i]);
        int icb = __builtin_amdgcn_readfirstlane(s_ib[i]);
        float mw = icw >= 0 ? 1.0f : 0.0f;
        float mb = icb >= 0 ? 1.0f : 0.0f;
        int ow = (icw >= 0 ? icw : 0) * ROWLEN;
        int ob = (icb >= 0 ? icb : 0) * ROWLEN;
        accw = fmaf(ft_w[ow + t], mw, accw);
        accb = fmaf(ft_w[ob + t], mb, accb);
    }
    if (t == 0 || t == 64) {
        const int* idx = (t == 0) ? s_iw : s_ib;
        float ps = 0.0f;
#pragma unroll
        for (int i = 0; i < MAX_FTS; ++i) {
            int ic = idx[i];
            float m = ic >= 0 ? 1.0f : 0.0f;
            int o = (ic >= 0 ? ic : 0) * ROWLEN;
            ps = fmaf(ft_w[o + HALF], m, ps);
        }
        s_ps[t == 0 ? 0 : 1] = ps;
    }
    const float st = stm[s];
    float xl = (1.0f - st) * accw + st * accb;
    float xh = (1.0f - st) * accb + st * accw;
    s_xx[t]        = fminf(fmaxf(xl, 0.0f), 1.0f);
    s_xx[t + HALF] = fminf(fmaxf(xh, 0.0f), 1.0f);
    __syncthreads();

    const int j = t >> 3, p = t & 7;
    const float* w1 = fc1_w + j * (2 * HALF);
    float part = 0.0f;
#pragma unroll
    for (int i = 0; i < 64; ++i) {
        int k = (i << 3) | p;
        part = fmaf(s_xx[k], w1[k], part);
    }
    part += __shfl_xor(part, 1, 64);
    part += __shfl_xor(part, 2, 64);
    part += __shfl_xor(part, 4, 64);
    if (p == 0) s_a[j] = fminf(fmaxf(part + fc1_b[j], 0.0f), 1.0f);
    __syncthreads();

    if (t < 32) {
        float a = fc2_b[t];
        const float* w2 = fc2_w + t * 32;
#pragma unroll
        for (int k = 0; k < 32; ++k) a = fmaf(s_a[k], w2[k], a);
        s_b[t] = fminf(fmaxf(a, 0.0f), 1.0f);
    }
    __syncthreads();

    if (t == 0) {
        float o = fco_b[0];
#pragma unroll
        for (int k = 0; k < 32; ++k) o = fmaf(s_b[k], fco_w[k], o);
        o += (s_ps[0] - s_ps[1]) * (0.5f - st);
        out[s] = o;
    }
}

extern "C" void kernel_launch(void* const* d_in, const int* in_sizes, int n_in,
                              void* d_out, int out_size, void* d_ws, size_t ws_size,
                              hipStream_t stream) {
    const int*   wft   = (const int*)  d_in[0];
    const int*   bft   = (const int*)  d_in[1];
    const float* stm   = (const float*)d_in[2];
    const float* ft_w  = (const float*)d_in[3];
    const float* ft_b  = (const float*)d_in[4];
    const float* fc1_w = (const float*)d_in[5];
    const float* fc1_b = (const float*)d_in[6];
    const float* fc2_w = (const float*)d_in[7];
    const float* fc2_b = (const float*)d_in[8];
    const float* fco_w = (const float*)d_in[9];
    const float* fco_b = (const float*)d_in[10];
    float* out = (float*)d_out;

    const int B     = in_sizes[0] / MAX_FTS;
    const int n_fts = in_sizes[3] / ROWLEN;

    const size_t colpad = (((size_t)(n_fts + 1) * sizeof(float)) + 15) & ~(size_t)15;
    const size_t w1f_b  = 16384 * sizeof(_Float16);           // 32 KB
    const size_t w2f_b  = 1024 * sizeof(_Float16);            // 2 KB
    const size_t tbl_b  = (size_t)(n_fts + 1) * 256;
    const size_t need   = 2 * colpad + w1f_b + w2f_b + tbl_b;

    const int nbq = (n_fts + 7) / 8;   // must also cover frag-building range

    if (ws_size >= need && (B & 15) == 0 && nbq >= 69) {
        char* p = (char*)d_ws;
        float*         scl  = (float*)p;                 p += colpad;
        float*         psq  = (float*)p;                 p += colpad;
        _Float16*      w1f  = (_Float16*)p;              p += w1f_b;
        _Float16*      w2f  = (_Float16*)p;              p += w2f_b;
        unsigned char* tbl8 = (unsigned char*)p;

        prep<<<nbq, 256, 0, stream>>>(ft_w, fc1_w, fc2_w, tbl8, scl, psq, w1f, w2f, n_fts);
        k_fused<<<B / 16, 512, 0, stream>>>(wft, bft, stm, tbl8, scl, psq, ft_b,
                                            w1f, w2f, fc1_b, fc2_b, fco_w, fco_b,
                                            out, n_fts);
    } else {
        nnue_fwd<<<B, 256, 0, stream>>>(wft, bft, stm, ft_w, ft_b,
                                        fc1_w, fc1_b, fc2_w, fc2_b,
                                        fco_w, fco_b, out);
    }
}